// Round 4
// baseline (282.090 us; speedup 1.0000x reference)
//
#include <hip/hip_runtime.h>

// ---------------------------------------------------------------------------
// SpatialHead, round 6: eliminate the staging pack entirely.
// - prep converts features fp32->bf16 once (fb, NHWC256 bf16, BW-bound).
// - conv-style kernels stage via __builtin_amdgcn_global_load_lds straight
//   into the stride-72 LDS tile (9 x 16B slots per px; pad slot + OOB lanes
//   source a zeroed global line). Zero VALU, zero transit VGPRs.
// - 256-thr blocks, 4 waves = (rp: row pair, kh: K-half); acc[2 rows][2 oc]
//   so each LDS frag read and each weight load feeds 2 MFMAs. kh partials
//   reduced through the dead tile. 4 blocks/CU.
// deform unchanged (round-4 version).
// ---------------------------------------------------------------------------

typedef unsigned short u16;
typedef unsigned int u32;
typedef __attribute__((ext_vector_type(8)))  short bf16x8;
typedef __attribute__((ext_vector_type(16))) float f32x16;

#define EPSBN 1e-5f

__device__ __forceinline__ u16 f2bf(float f) {          // RNE fp32->bf16
  u32 u = __builtin_bit_cast(u32, f);
  u32 r = u + 0x7FFFu + ((u >> 16) & 1u);
  return (u16)(r >> 16);
}
__device__ __forceinline__ u32 pk2(float a, float b) {
  return (u32)f2bf(a) | ((u32)f2bf(b) << 16);
}
__device__ __forceinline__ float lo2f(u32 w) { return __builtin_bit_cast(float, w << 16); }
__device__ __forceinline__ float hi2f(u32 w) { return __builtin_bit_cast(float, w & 0xFFFF0000u); }

__device__ __forceinline__ void gload_lds16(const void* g, void* l) {
  __builtin_amdgcn_global_load_lds(
      (const __attribute__((address_space(1))) unsigned int*)g,
      (__attribute__((address_space(3))) unsigned int*)l, 16, 0, 0);
}

// ---------------------------------------------------------------------------
// Weight fragment counts (u16):
//  wcf: [cc4][tap9][h4][nt2]*512        = 147456
//  wcc: [tap9][nt2]*512                 = 9216    (coord xx/yy channels)
//  wof: [tap9][h4]*512                  = 18432   (oc padded 18->32)
//  wdf/wr1/wr2: [tap9][h4][nt2]*512     = 36864 each
// ---------------------------------------------------------------------------
#define N_WCF 147456
#define N_WCC 9216
#define N_WOF 18432
#define N_W64 36864
#define N_ALLW (N_WCF + N_WCC + N_WOF + 3*N_W64)   // 285696

#define FBK_BLOCKS 9216          // 18,874,368 elems / (256 thr * 8)
#define WT_BLOCKS  1116

__global__ __launch_bounds__(256) void prep_kernel(
    const float* __restrict__ feat,
    const float* __restrict__ coord_w, const float* __restrict__ off_w,
    const float* __restrict__ dc_w, const float* __restrict__ r1_w,
    const float* __restrict__ r2_w,
    u16* __restrict__ fb,
    u16* __restrict__ wcf, u16* __restrict__ wcc, u16* __restrict__ wof,
    u16* __restrict__ wdf, u16* __restrict__ wr1, u16* __restrict__ wr2,
    u32* __restrict__ zb)
{
  const int t = threadIdx.x;
  if (blockIdx.x < FBK_BLOCKS) {           // fp32 -> bf16 feature conversion
    const int e = (blockIdx.x * 256 + t) * 8;
    const float4 f0 = *(const float4*)(feat + e);
    const float4 f1 = *(const float4*)(feat + e + 4);
    uint4 o;
    o.x = pk2(f0.x, f0.y); o.y = pk2(f0.z, f0.w);
    o.z = pk2(f1.x, f1.y); o.w = pk2(f1.z, f1.w);
    *(uint4*)(fb + e) = o;
    return;
  }
  int i = (blockIdx.x - FBK_BLOCKS) * 256 + t;
  if (i < 64) zb[i] = 0u;                  // zeroed line for OOB/pad staging
  if (i >= N_ALLW) return;
  int d = i;
  if (d < N_WCF) {
    int j = d & 7, lane = (d >> 3) & 63, frag = d >> 9;
    int nt = frag & 1, h = (frag >> 1) & 3, tap = (frag >> 3) % 9, cc = (frag >> 3) / 9;
    int ic = cc * 64 + h * 16 + ((lane >> 5) << 3) + j;
    int oc = nt * 32 + (lane & 31);
    wcf[d] = f2bf(coord_w[((size_t)oc * 258 + ic) * 9 + tap]);
    return;
  }
  d -= N_WCF;
  if (d < N_WCC) {
    int j = d & 7, lane = (d >> 3) & 63, frag = d >> 9;
    int nt = frag & 1, tap = frag >> 1;
    int ic = 256 + ((lane >> 5) << 3) + j;
    int oc = nt * 32 + (lane & 31);
    wcc[d] = (ic < 258) ? f2bf(coord_w[((size_t)oc * 258 + ic) * 9 + tap]) : (u16)0;
    return;
  }
  d -= N_WCC;
  if (d < N_WOF) {
    int j = d & 7, lane = (d >> 3) & 63, frag = d >> 9;
    int h = frag & 3, tap = frag >> 2;
    int ic = h * 16 + ((lane >> 5) << 3) + j;
    int oc = lane & 31;
    wof[d] = (oc < 18) ? f2bf(off_w[((size_t)oc * 64 + ic) * 9 + tap]) : (u16)0;
    return;
  }
  d -= N_WOF;
  int seg = d / N_W64;
  int e = d - seg * N_W64;
  int j = e & 7, lane = (e >> 3) & 63, frag = e >> 9;
  int nt = frag & 1, h = (frag >> 1) & 3, tap = frag >> 3;
  int ic = h * 16 + ((lane >> 5) << 3) + j;
  int oc = nt * 32 + (lane & 31);
  const float* src = (seg == 0) ? dc_w : (seg == 1) ? r1_w : r2_w;
  u16* dst = (seg == 0) ? wdf : (seg == 1) ? wr1 : wr2;
  dst[e] = f2bf(src[((size_t)oc * 64 + ic) * 9 + tap]);
}

// ---------------------------------------------------------------------------
// Staging descriptor helper: tile has 204 px (6x34), 9 slots of 16B per px
// (8 data + 1 pad). Issue j covers slots j*64+lane. desc = byte offset into
// the source (px_stride_bytes per px, 16B per part) or ~0 for pad/OOB.
// ---------------------------------------------------------------------------
__device__ __forceinline__ u32 stage_desc(int slot, int x0, int y0, int b,
                                          int px_stride) {
  const int px = slot / 9, part = slot - px * 9;
  if (part >= 8 || px >= 204) return 0xFFFFFFFFu;
  const int ly = px / 34, lx = px - ly * 34;
  const int gy = y0 + ly - 1, gx = x0 + lx - 1;
  if ((unsigned)gy >= 96u || (unsigned)gx >= 96u) return 0xFFFFFFFFu;
  return (u32)(((b * 96 + gy) * 96 + gx) * px_stride + part * 16);
}

// ---------------------------------------------------------------------------
// Coord conv 258->64 + BN1 + ReLU -> x1b (bf16 NHWC64).
// 256 thr, 4 waves = (rp: rows 2rp..2rp+1, kh: h-pair). acc[ai2][nt2].
// Staging: 8 global_load_lds per wave per cc (32 issues = 2048 slots).
// ---------------------------------------------------------------------------
__global__ __launch_bounds__(256, 4) void coord_conv_kernel(
    const u16* __restrict__ fb, const u16* __restrict__ wcf,
    const u16* __restrict__ wcc, const float* __restrict__ cb,
    const float* __restrict__ g, const float* __restrict__ bb,
    const float* __restrict__ m, const float* __restrict__ v,
    u16* __restrict__ x1b, const u32* __restrict__ zb)
{
  __shared__ __align__(16) u16 tile[16384];   // 32 KB = 2048 slots
  __shared__ __align__(16) u16 ct[204 * 16];  // 6528 B coord channels
  const int t = threadIdx.x;
  const int wv = t >> 6, lane = t & 63;
  const int l31 = lane & 31, l5 = lane >> 5;
  const int rp = wv & 1, kh = wv >> 1;
  const int x0 = blockIdx.x * 32, y0 = blockIdx.y * 4, b = blockIdx.z;

  u32 desc[8];
  #pragma unroll
  for (int k = 0; k < 8; ++k)
    desc[k] = stage_desc((wv + 4 * k) * 64 + lane, x0, y0, b, 512);

  // coord channels LDS (ch0=xx, ch1=yy, rest 0), written once
  if (t < 204) {
    const int ly = t / 34, lx = t - ly * 34;
    const int gy = y0 + ly - 1, gx = x0 + lx - 1;
    uint4 o0 = {0u, 0u, 0u, 0u}, o1 = {0u, 0u, 0u, 0u};
    if ((unsigned)gy < 96u && (unsigned)gx < 96u) {
      const float xx = -1.f + (2.f / 95.f) * (float)gx;
      const float yy = -1.f + (2.f / 95.f) * (float)gy;
      o0.x = pk2(xx, yy);
    }
    *(uint4*)(ct + t * 16) = o0;
    *(uint4*)(ct + t * 16 + 8) = o1;
  }

  f32x16 acc[2][2] = {};   // [ai row][nt oc-tile]

  for (int cc = 0; cc < 4; ++cc) {
    #pragma unroll
    for (int k = 0; k < 8; ++k) {
      const char* src = (desc[k] == 0xFFFFFFFFu)
          ? (const char*)zb : (const char*)fb + desc[k] + cc * 128;
      gload_lds16(src, (char*)tile + (wv + 4 * k) * 1024);
    }
    __syncthreads();
    #pragma unroll
    for (int tap = 0; tap < 9; ++tap) {
      const int dy = tap / 3, dx = tap - dy * 3;
      #pragma unroll
      for (int hh = 0; hh < 2; ++hh) {
        const int h = kh * 2 + hh;
        const bf16x8 a0 = *(const bf16x8*)(tile +
            ((rp * 2 + 0 + dy) * 34 + l31 + dx) * 72 + h * 16 + l5 * 8);
        const bf16x8 a1 = *(const bf16x8*)(tile +
            ((rp * 2 + 1 + dy) * 34 + l31 + dx) * 72 + h * 16 + l5 * 8);
        #pragma unroll
        for (int nt = 0; nt < 2; ++nt) {
          const bf16x8 bfr = *(const bf16x8*)(wcf +
              ((size_t)((((cc * 9 + tap) * 4 + h) * 2) + nt)) * 512 + lane * 8);
          acc[0][nt] = __builtin_amdgcn_mfma_f32_32x32x16_bf16(a0, bfr,
                                                               acc[0][nt], 0, 0, 0);
          acc[1][nt] = __builtin_amdgcn_mfma_f32_32x32x16_bf16(a1, bfr,
                                                               acc[1][nt], 0, 0, 0);
        }
      }
    }
    __syncthreads();
  }

  // coordinate K-step (kh==0 waves only)
  if (kh == 0) {
    #pragma unroll
    for (int tap = 0; tap < 9; ++tap) {
      const int dy = tap / 3, dx = tap - dy * 3;
      const bf16x8 a0 = *(const bf16x8*)(ct +
          ((rp * 2 + 0 + dy) * 34 + l31 + dx) * 16 + l5 * 8);
      const bf16x8 a1 = *(const bf16x8*)(ct +
          ((rp * 2 + 1 + dy) * 34 + l31 + dx) * 16 + l5 * 8);
      #pragma unroll
      for (int nt = 0; nt < 2; ++nt) {
        const bf16x8 bfr = *(const bf16x8*)(wcc +
            ((size_t)(tap * 2 + nt)) * 512 + lane * 8);
        acc[0][nt] = __builtin_amdgcn_mfma_f32_32x32x16_bf16(a0, bfr,
                                                             acc[0][nt], 0, 0, 0);
        acc[1][nt] = __builtin_amdgcn_mfma_f32_32x32x16_bf16(a1, bfr,
                                                             acc[1][nt], 0, 0, 0);
      }
    }
  }

  // kh reduction through the dead tile (32 KB exactly)
  float* redk = (float*)tile;
  __syncthreads();
  if (kh == 1) {
    #pragma unroll
    for (int ai = 0; ai < 2; ++ai)
      #pragma unroll
      for (int nt = 0; nt < 2; ++nt)
        #pragma unroll
        for (int r = 0; r < 16; ++r)
          redk[(((rp * 2 + ai) * 2 + nt) * 16 + r) * 64 + lane] = acc[ai][nt][r];
  }
  __syncthreads();
  if (kh == 0) {
    #pragma unroll
    for (int ai = 0; ai < 2; ++ai)
      #pragma unroll
      for (int nt = 0; nt < 2; ++nt) {
        #pragma unroll
        for (int r = 0; r < 16; ++r)
          acc[ai][nt][r] += redk[(((rp * 2 + ai) * 2 + nt) * 16 + r) * 64 + lane];
        const int oc = nt * 32 + l31;
        const float inv = g[oc] * rsqrtf(v[oc] + EPSBN);
        const float sh = bb[oc] - m[oc] * inv + cb[oc] * inv;
        const int y = y0 + rp * 2 + ai;
        #pragma unroll
        for (int r = 0; r < 16; ++r) {
          const int xr = (r & 3) + 8 * (r >> 2) + 4 * l5;
          const float val = fmaxf(fmaf(acc[ai][nt][r], inv, sh), 0.f);
          x1b[((size_t)((b * 96 + y) * 96 + x0 + xr)) * 64 + oc] = f2bf(val);
        }
      }
  }
}

// ---------------------------------------------------------------------------
// 64->64ch 3x3 conv (bf16 NHWC64 in). 256 thr, 4 waves = (rp, kh).
// acc[ai2][NN]. Staging: single-shot global_load_lds (32 issues).
// EPI: 0 = BN+ReLU -> bf16 ; 1 = +bias -> fp32 NHWC18 ; 2 = BN+ReLU +
//      1x1 out conv + sigmoid -> fp32 (B,96,96).
// ---------------------------------------------------------------------------
template<int NN, int EPI>
__global__ __launch_bounds__(256, 4) void conv64_kernel(
    const u16* __restrict__ xin, const u16* __restrict__ wf,
    const float* __restrict__ bias,
    const float* __restrict__ g, const float* __restrict__ bb,
    const float* __restrict__ m, const float* __restrict__ v,
    const float* __restrict__ ow, const float* __restrict__ ob,
    void* __restrict__ outp, const u32* __restrict__ zb)
{
  __shared__ __align__(16) u16 tile[16384];
  __shared__ float red2[128];
  const int t = threadIdx.x;
  const int wv = t >> 6, lane = t & 63;
  const int l31 = lane & 31, l5 = lane >> 5;
  const int rp = wv & 1, kh = wv >> 1;
  const int x0 = blockIdx.x * 32, y0 = blockIdx.y * 4, b = blockIdx.z;

  #pragma unroll
  for (int k = 0; k < 8; ++k) {
    const u32 d = stage_desc((wv + 4 * k) * 64 + lane, x0, y0, b, 128);
    const char* src = (d == 0xFFFFFFFFu) ? (const char*)zb
                                         : (const char*)xin + d;
    gload_lds16(src, (char*)tile + (wv + 4 * k) * 1024);
  }
  __syncthreads();

  f32x16 acc[2][NN] = {};
  #pragma unroll
  for (int tap = 0; tap < 9; ++tap) {
    const int dy = tap / 3, dx = tap - dy * 3;
    #pragma unroll
    for (int hh = 0; hh < 2; ++hh) {
      const int h = kh * 2 + hh;
      const bf16x8 a0 = *(const bf16x8*)(tile +
          ((rp * 2 + 0 + dy) * 34 + l31 + dx) * 72 + h * 16 + l5 * 8);
      const bf16x8 a1 = *(const bf16x8*)(tile +
          ((rp * 2 + 1 + dy) * 34 + l31 + dx) * 72 + h * 16 + l5 * 8);
      #pragma unroll
      for (int nt = 0; nt < NN; ++nt) {
        const size_t f = (NN == 2) ? (size_t)((tap * 4 + h) * 2 + nt)
                                   : (size_t)(tap * 4 + h);
        const bf16x8 bfr = *(const bf16x8*)(wf + f * 512 + lane * 8);
        acc[0][nt] = __builtin_amdgcn_mfma_f32_32x32x16_bf16(a0, bfr,
                                                             acc[0][nt], 0, 0, 0);
        acc[1][nt] = __builtin_amdgcn_mfma_f32_32x32x16_bf16(a1, bfr,
                                                             acc[1][nt], 0, 0, 0);
      }
    }
  }

  // kh reduction through the dead tile
  float* redk = (float*)tile;
  __syncthreads();
  if (kh == 1) {
    #pragma unroll
    for (int ai = 0; ai < 2; ++ai)
      #pragma unroll
      for (int nt = 0; nt < NN; ++nt)
        #pragma unroll
        for (int r = 0; r < 16; ++r)
          redk[(((rp * 2 + ai) * NN + nt) * 16 + r) * 64 + lane] = acc[ai][nt][r];
  }
  __syncthreads();

  if constexpr (EPI == 0) {
    if (kh == 0) {
      u16* xo = (u16*)outp;
      #pragma unroll
      for (int ai = 0; ai < 2; ++ai)
        #pragma unroll
        for (int nt = 0; nt < NN; ++nt) {
          #pragma unroll
          for (int r = 0; r < 16; ++r)
            acc[ai][nt][r] += redk[(((rp * 2 + ai) * NN + nt) * 16 + r) * 64 + lane];
          const int oc = nt * 32 + l31;
          const float inv = g[oc] * rsqrtf(v[oc] + EPSBN);
          const float sh = bb[oc] - m[oc] * inv;
          const int y = y0 + rp * 2 + ai;
          #pragma unroll
          for (int r = 0; r < 16; ++r) {
            const int xr = (r & 3) + 8 * (r >> 2) + 4 * l5;
            const float val = fmaxf(fmaf(acc[ai][nt][r], inv, sh), 0.f);
            xo[((size_t)((b * 96 + y) * 96 + x0 + xr)) * 64 + oc] = f2bf(val);
          }
        }
    }
  } else if constexpr (EPI == 1) {
    if (kh == 0) {
      float* fo = (float*)outp;
      #pragma unroll
      for (int ai = 0; ai < 2; ++ai) {
        #pragma unroll
        for (int r = 0; r < 16; ++r)
          acc[ai][0][r] += redk[(((rp * 2 + ai) * NN + 0) * 16 + r) * 64 + lane];
        if (l31 < 18) {
          const float bs = bias[l31];
          const int y = y0 + rp * 2 + ai;
          #pragma unroll
          for (int r = 0; r < 16; ++r) {
            const int xr = (r & 3) + 8 * (r >> 2) + 4 * l5;
            fo[((size_t)((b * 96 + y) * 96 + x0 + xr)) * 18 + l31] =
                acc[ai][0][r] + bs;
          }
        }
      }
    }
  } else {  // EPI == 2
    if (kh == 0) {
      #pragma unroll
      for (int ai = 0; ai < 2; ++ai) {
        float pr[16];
        #pragma unroll
        for (int r = 0; r < 16; ++r) pr[r] = 0.f;
        #pragma unroll
        for (int nt = 0; nt < NN; ++nt) {
          const int oc = nt * 32 + l31;
          const float inv = g[oc] * rsqrtf(v[oc] + EPSBN);
          const float sh = bb[oc] - m[oc] * inv;
          const float wo = ow[oc];
          #pragma unroll
          for (int r = 0; r < 16; ++r) {
            const float a = acc[ai][nt][r] +
                redk[(((rp * 2 + ai) * NN + nt) * 16 + r) * 64 + lane];
            const float val = fmaxf(fmaf(a, inv, sh), 0.f);
            pr[r] = fmaf(val, wo, pr[r]);
          }
        }
        #pragma unroll
        for (int mask = 1; mask <= 16; mask <<= 1)
          #pragma unroll
          for (int r = 0; r < 16; ++r)
            pr[r] += __shfl_xor(pr[r], mask);
        if (l31 == 0) {
          #pragma unroll
          for (int r = 0; r < 16; ++r) {
            const int xr = (r & 3) + 8 * (r >> 2) + 4 * l5;
            red2[(rp * 2 + ai) * 32 + xr] = pr[r];
          }
        }
      }
    }
    __syncthreads();
    if (t < 128) {
      float* fo = (float*)outp;
      const int yy = y0 + (t >> 5), xx = x0 + (t & 31);
      const float val = red2[t] + ob[0];
      fo[(size_t)(b * 96 + yy) * 96 + xx] = 1.f / (1.f + expf(-val));
    }
  }
}

// ---------------------------------------------------------------------------
// Deformable conv 64->64 + BN2 + ReLU -> x2b (round-4 version, unchanged).
// ---------------------------------------------------------------------------
__global__ __launch_bounds__(512, 4) void deform_kernel(
    const u16* __restrict__ x1b, const float* __restrict__ off,
    const u16* __restrict__ wdf,
    const float* __restrict__ g, const float* __restrict__ bb,
    const float* __restrict__ m, const float* __restrict__ v,
    u16* __restrict__ x2b)
{
  __shared__ __align__(16) u16 s[2 * 128 * 72];   // 36864 B
  __shared__ float offs[128 * 18];                //  9216 B
  const int t = threadIdx.x;
  const int wv = t >> 6, lane = t & 63;
  const int l31 = lane & 31, l5 = lane >> 5;
  const int mt = wv & 3, ntw = wv >> 2;
  const int x0 = blockIdx.x * 16, y0 = blockIdx.y * 8, b = blockIdx.z;

  {
    float po[5];
    #pragma unroll
    for (int r = 0; r < 5; ++r) {
      const int i = t + r * 512;
      po[r] = 0.f;
      if (i < 2304) {
        const int p = i / 18, c = i - p * 18;
        const int gy = y0 + (p >> 4), gx = x0 + (p & 15);
        po[r] = off[((size_t)((b * 96 + gy) * 96 + gx)) * 18 + c];
      }
    }
    #pragma unroll
    for (int r = 0; r < 5; ++r) {
      const int i = t + r * 512;
      if (i < 2304) offs[i] = po[r];
    }
  }
  __syncthreads();

  const int sp = t >> 2, part = t & 3;
  const int sy = y0 + (sp >> 4), sx = x0 + (sp & 15);

  uint4 gbuf[8];
  float w4[4];

  auto prefetch = [&](int k) {
    const float oy = offs[sp * 18 + 2 * k];
    const float ox = offs[sp * 18 + 2 * k + 1];
    const float py = (float)(sy + k / 3 - 1) + oy;
    const float px = (float)(sx + k % 3 - 1) + ox;
    const float yf = floorf(py), xf = floorf(px);
    const float fy = py - yf, fx = px - xf;
    const int yi = (int)yf, xi = (int)xf;
    #pragma unroll
    for (int cor = 0; cor < 4; ++cor) {
      const int cy = yi + (cor >> 1), cx = xi + (cor & 1);
      const uint4 z = {0u, 0u, 0u, 0u};
      gbuf[2 * cor] = z; gbuf[2 * cor + 1] = z;
      const float wy = (cor & 2) ? fy : 1.f - fy;
      const float wx = (cor & 1) ? fx : 1.f - fx;
      w4[cor] = 0.f;
      if ((unsigned)cy < 96u && (unsigned)cx < 96u) {
        w4[cor] = wy * wx;
        const u16* p = x1b + ((size_t)((b * 96 + cy) * 96 + cx)) * 64
                       + part * 16;
        gbuf[2 * cor]     = *(const uint4*)p;
        gbuf[2 * cor + 1] = *(const uint4*)(p + 8);
      }
    }
  };
  auto combine = [&](u16* dst) {
    float val[16];
    #pragma unroll
    for (int j = 0; j < 16; ++j) val[j] = 0.f;
    #pragma unroll
    for (int cor = 0; cor < 4; ++cor) {
      const float wgt = w4[cor];
      const u32 uu[8] = {gbuf[2 * cor].x, gbuf[2 * cor].y,
                         gbuf[2 * cor].z, gbuf[2 * cor].w,
                         gbuf[2 * cor + 1].x, gbuf[2 * cor + 1].y,
                         gbuf[2 * cor + 1].z, gbuf[2 * cor + 1].w};
      #pragma unroll
      for (int u = 0; u < 8; ++u) {
        val[2 * u]     = fmaf(wgt, lo2f(uu[u]), val[2 * u]);
        val[2 * u + 1] = fmaf(wgt, hi2f(uu[u]), val[2 * u + 1]);
      }
    }
    u32 pk[8];
    #pragma unroll
    for (int u = 0; u < 8; ++u) pk[u] = pk2(val[2 * u], val[2 * u + 1]);
    uint4 w0 = {pk[0], pk[1], pk[2], pk[3]};
    uint4 w1 = {pk[4], pk[5], pk[6], pk[7]};
    *(uint4*)(dst + sp * 72 + part * 16) = w0;
    *(uint4*)(dst + sp * 72 + part * 16 + 8) = w1;
  };

  f32x16 acc = {};

  prefetch(0);
  combine(s);          // buffer 0
  __syncthreads();

  for (int k = 0; k < 9; ++k) {
    u16* cur = s + (k & 1) * 9216;
    if (k < 8) prefetch(k + 1);          // gathers fly during MFMAs
    #pragma unroll
    for (int h = 0; h < 4; ++h) {
      const bf16x8 afr = *(const bf16x8*)(cur + (mt * 32 + l31) * 72
                                          + h * 16 + l5 * 8);
      const bf16x8 bfr = *(const bf16x8*)(wdf +
          ((size_t)((k * 4 + h) * 2 + ntw)) * 512 + lane * 8);
      acc = __builtin_amdgcn_mfma_f32_32x32x16_bf16(afr, bfr, acc, 0, 0, 0);
    }
    if (k < 8) combine(s + ((k + 1) & 1) * 9216);
    __syncthreads();
  }

  const int oc = ntw * 32 + l31;
  const float inv = g[oc] * rsqrtf(v[oc] + EPSBN);
  const float sh = bb[oc] - m[oc] * inv;
  #pragma unroll
  for (int r = 0; r < 16; ++r) {
    const int pxi = mt * 32 + (r & 3) + 8 * (r >> 2) + 4 * l5;
    const int y = y0 + (pxi >> 4), x = x0 + (pxi & 15);
    const float val = fmaxf(fmaf(acc[r], inv, sh), 0.f);
    x2b[((size_t)((b * 96 + y) * 96 + x)) * 64 + oc] = f2bf(val);
  }
}

extern "C" void kernel_launch(void* const* d_in, const int* in_sizes, int n_in,
                              void* d_out, int out_size, void* d_ws,
                              size_t ws_size, hipStream_t stream)
{
  (void)in_sizes; (void)n_in; (void)out_size; (void)ws_size;
  const float* features = (const float*)d_in[0];
  const float* coord_w  = (const float*)d_in[1];
  const float* coord_b  = (const float*)d_in[2];
  const float* bn1g = (const float*)d_in[3];
  const float* bn1b = (const float*)d_in[4];
  const float* bn1m = (const float*)d_in[5];
  const float* bn1v = (const float*)d_in[6];
  const float* off_w = (const float*)d_in[7];
  const float* off_b = (const float*)d_in[8];
  const float* dc_w  = (const float*)d_in[9];
  const float* bn2g = (const float*)d_in[10];
  const float* bn2b = (const float*)d_in[11];
  const float* bn2m = (const float*)d_in[12];
  const float* bn2v = (const float*)d_in[13];
  const float* r1_w = (const float*)d_in[14];
  const float* bn3g = (const float*)d_in[15];
  const float* bn3b = (const float*)d_in[16];
  const float* bn3m = (const float*)d_in[17];
  const float* bn3v = (const float*)d_in[18];
  const float* r2_w = (const float*)d_in[19];
  const float* bn4g = (const float*)d_in[20];
  const float* bn4b = (const float*)d_in[21];
  const float* bn4m = (const float*)d_in[22];
  const float* bn4v = (const float*)d_in[23];
  const float* out_w = (const float*)d_in[24];
  const float* out_b = (const float*)d_in[25];

  char* W = (char*)d_ws;
  float* offb = (float*)W;                         //  5,308,416 B
  u16*   x1b  = (u16*)(W + 5308416);               //  9,437,184 B
  u16*   x2b  = (u16*)(W + 14745600);
  u16*   x3b  = (u16*)(W + 24182784);
  u16*   wcf  = (u16*)(W + 33619968);
  u16*   wcc  = wcf + N_WCF;
  u16*   wof  = wcc + N_WCC;
  u16*   wdf  = wof + N_WOF;
  u16*   wr1  = wdf + N_W64;
  u16*   wr2  = wr1 + N_W64;
  u16*   fb   = (u16*)(W + 34191360);              // 37,748,736 B bf16 feats
  u32*   zb   = (u32*)(W + 71940096);              // 256 B zero line

  prep_kernel<<<FBK_BLOCKS + WT_BLOCKS, 256, 0, stream>>>(
      features, coord_w, off_w, dc_w, r1_w, r2_w,
      fb, wcf, wcc, wof, wdf, wr1, wr2, zb);

  dim3 grid(3, 24, 8);   // 32x4 tiles
  dim3 gridD(6, 12, 8);  // 16x8 tiles (deform)

  coord_conv_kernel<<<grid, 256, 0, stream>>>(
      fb, wcf, wcc, coord_b, bn1g, bn1b, bn1m, bn1v, x1b, zb);
  conv64_kernel<1, 1><<<grid, 256, 0, stream>>>(
      x1b, wof, off_b, nullptr, nullptr, nullptr, nullptr, nullptr, nullptr,
      (void*)offb, zb);
  deform_kernel<<<gridD, 512, 0, stream>>>(
      x1b, offb, wdf, bn2g, bn2b, bn2m, bn2v, x2b);
  conv64_kernel<2, 0><<<grid, 256, 0, stream>>>(
      x2b, wr1, nullptr, bn3g, bn3b, bn3m, bn3v, nullptr, nullptr,
      (void*)x3b, zb);
  conv64_kernel<2, 2><<<grid, 256, 0, stream>>>(
      x3b, wr2, nullptr, bn4g, bn4b, bn4m, bn4v, out_w, out_b, d_out, zb);
}

// Round 5
// 268.514 us; speedup vs baseline: 1.0506x; 1.0506x over previous
//
#include <hip/hip_runtime.h>

// ---------------------------------------------------------------------------
// SpatialHead, round 7: gload_lds staging (dbuf) + batch weight reg-preload
// + 4-rows-per-wave (weights/LDS frags reused 4x).
// conv-style kernels: 256 thr, 4 waves = (ntw: oc tile, kh: K-half),
// each wave computes ALL 4 rows (acc[4] in AGPR).
//  - staging: __builtin_amdgcn_global_load_lds into stride-72 tile,
//    double-buffered across cc chunks (coord) / single shot (conv64).
//  - weights: wfr[18] batch-preloaded per cc (one L2 latency, not 36).
//  - kh partials reduced through the dead tile.
// prep converts features fp32->bf16 once (fb); deform = round-4 version.
// ---------------------------------------------------------------------------

typedef unsigned short u16;
typedef unsigned int u32;
typedef __attribute__((ext_vector_type(8)))  short bf16x8;
typedef __attribute__((ext_vector_type(16))) float f32x16;

#define EPSBN 1e-5f

__device__ __forceinline__ u16 f2bf(float f) {          // RNE fp32->bf16
  u32 u = __builtin_bit_cast(u32, f);
  u32 r = u + 0x7FFFu + ((u >> 16) & 1u);
  return (u16)(r >> 16);
}
__device__ __forceinline__ u32 pk2(float a, float b) {
  return (u32)f2bf(a) | ((u32)f2bf(b) << 16);
}
__device__ __forceinline__ float lo2f(u32 w) { return __builtin_bit_cast(float, w << 16); }
__device__ __forceinline__ float hi2f(u32 w) { return __builtin_bit_cast(float, w & 0xFFFF0000u); }

__device__ __forceinline__ void gload_lds16(const void* g, void* l) {
  __builtin_amdgcn_global_load_lds(
      (const __attribute__((address_space(1))) unsigned int*)g,
      (__attribute__((address_space(3))) unsigned int*)l, 16, 0, 0);
}

// ---------------------------------------------------------------------------
// Weight fragment counts (u16):
//  wcf: [cc4][tap9][h4][nt2]*512        = 147456
//  wcc: [tap9][nt2]*512                 = 9216    (coord xx/yy channels)
//  wof: [tap9][h4]*512                  = 18432   (oc padded 18->32)
//  wdf/wr1/wr2: [tap9][h4][nt2]*512     = 36864 each
// ---------------------------------------------------------------------------
#define N_WCF 147456
#define N_WCC 9216
#define N_WOF 18432
#define N_W64 36864
#define N_ALLW (N_WCF + N_WCC + N_WOF + 3*N_W64)   // 285696

#define FBK_BLOCKS 9216          // 18,874,368 elems / (256 thr * 8)
#define WT_BLOCKS  1116

__global__ __launch_bounds__(256) void prep_kernel(
    const float* __restrict__ feat,
    const float* __restrict__ coord_w, const float* __restrict__ off_w,
    const float* __restrict__ dc_w, const float* __restrict__ r1_w,
    const float* __restrict__ r2_w,
    u16* __restrict__ fb,
    u16* __restrict__ wcf, u16* __restrict__ wcc, u16* __restrict__ wof,
    u16* __restrict__ wdf, u16* __restrict__ wr1, u16* __restrict__ wr2,
    u32* __restrict__ zb)
{
  const int t = threadIdx.x;
  if (blockIdx.x < FBK_BLOCKS) {           // fp32 -> bf16 feature conversion
    const int e = (blockIdx.x * 256 + t) * 8;
    const float4 f0 = *(const float4*)(feat + e);
    const float4 f1 = *(const float4*)(feat + e + 4);
    uint4 o;
    o.x = pk2(f0.x, f0.y); o.y = pk2(f0.z, f0.w);
    o.z = pk2(f1.x, f1.y); o.w = pk2(f1.z, f1.w);
    *(uint4*)(fb + e) = o;
    return;
  }
  int i = (blockIdx.x - FBK_BLOCKS) * 256 + t;
  if (i < 64) zb[i] = 0u;                  // zeroed line for OOB/pad staging
  if (i >= N_ALLW) return;
  int d = i;
  if (d < N_WCF) {
    int j = d & 7, lane = (d >> 3) & 63, frag = d >> 9;
    int nt = frag & 1, h = (frag >> 1) & 3, tap = (frag >> 3) % 9, cc = (frag >> 3) / 9;
    int ic = cc * 64 + h * 16 + ((lane >> 5) << 3) + j;
    int oc = nt * 32 + (lane & 31);
    wcf[d] = f2bf(coord_w[((size_t)oc * 258 + ic) * 9 + tap]);
    return;
  }
  d -= N_WCF;
  if (d < N_WCC) {
    int j = d & 7, lane = (d >> 3) & 63, frag = d >> 9;
    int nt = frag & 1, tap = frag >> 1;
    int ic = 256 + ((lane >> 5) << 3) + j;
    int oc = nt * 32 + (lane & 31);
    wcc[d] = (ic < 258) ? f2bf(coord_w[((size_t)oc * 258 + ic) * 9 + tap]) : (u16)0;
    return;
  }
  d -= N_WCC;
  if (d < N_WOF) {
    int j = d & 7, lane = (d >> 3) & 63, frag = d >> 9;
    int h = frag & 3, tap = frag >> 2;
    int ic = h * 16 + ((lane >> 5) << 3) + j;
    int oc = lane & 31;
    wof[d] = (oc < 18) ? f2bf(off_w[((size_t)oc * 64 + ic) * 9 + tap]) : (u16)0;
    return;
  }
  d -= N_WOF;
  int seg = d / N_W64;
  int e = d - seg * N_W64;
  int j = e & 7, lane = (e >> 3) & 63, frag = e >> 9;
  int nt = frag & 1, h = (frag >> 1) & 3, tap = frag >> 3;
  int ic = h * 16 + ((lane >> 5) << 3) + j;
  int oc = nt * 32 + (lane & 31);
  const float* src = (seg == 0) ? dc_w : (seg == 1) ? r1_w : r2_w;
  u16* dst = (seg == 0) ? wdf : (seg == 1) ? wr1 : wr2;
  dst[e] = f2bf(src[((size_t)oc * 64 + ic) * 9 + tap]);
}

// ---------------------------------------------------------------------------
// Staging descriptor: tile = 204 px (6x34), 9 slots of 16B per px (8 data +
// 1 pad). desc = byte offset into source or ~0 for pad/OOB (-> zb).
// ---------------------------------------------------------------------------
__device__ __forceinline__ u32 stage_desc(int slot, int x0, int y0, int b,
                                          int px_stride) {
  const int px = slot / 9, part = slot - px * 9;
  if (part >= 8 || px >= 204) return 0xFFFFFFFFu;
  const int ly = px / 34, lx = px - ly * 34;
  const int gy = y0 + ly - 1, gx = x0 + lx - 1;
  if ((unsigned)gy >= 96u || (unsigned)gx >= 96u) return 0xFFFFFFFFu;
  return (u32)(((b * 96 + gy) * 96 + gx) * px_stride + part * 16);
}

// ---------------------------------------------------------------------------
// Coord conv 258->64 + BN1 + ReLU -> x1b (bf16 NHWC64).
// 256 thr, 4 waves = (ntw, kh); each wave does 4 rows (acc[4]).
// LDS tile double-buffered across cc; wfr[18] preloaded per cc.
// ---------------------------------------------------------------------------
__global__ __launch_bounds__(256, 2) void coord_conv_kernel(
    const u16* __restrict__ fb, const u16* __restrict__ wcf,
    const u16* __restrict__ wcc, const float* __restrict__ cb,
    const float* __restrict__ g, const float* __restrict__ bb,
    const float* __restrict__ m, const float* __restrict__ v,
    u16* __restrict__ x1b, const u32* __restrict__ zb)
{
  __shared__ __align__(16) u16 tile[2][16384];  // 2 x 32 KB
  __shared__ __align__(16) u16 ct[204 * 16];    // 6528 B coord channels
  const int t = threadIdx.x;
  const int wv = t >> 6, lane = t & 63;
  const int l31 = lane & 31, l5 = lane >> 5;
  const int ntw = wv & 1, kh = wv >> 1;
  const int x0 = blockIdx.x * 32, y0 = blockIdx.y * 4, b = blockIdx.z;

  u32 desc[8];
  #pragma unroll
  for (int k = 0; k < 8; ++k)
    desc[k] = stage_desc((wv + 4 * k) * 64 + lane, x0, y0, b, 512);

  // coord channels LDS (ch0=xx, ch1=yy, rest 0), written once
  if (t < 204) {
    const int ly = t / 34, lx = t - ly * 34;
    const int gy = y0 + ly - 1, gx = x0 + lx - 1;
    uint4 o0 = {0u, 0u, 0u, 0u}, o1 = {0u, 0u, 0u, 0u};
    if ((unsigned)gy < 96u && (unsigned)gx < 96u) {
      const float xx = -1.f + (2.f / 95.f) * (float)gx;
      const float yy = -1.f + (2.f / 95.f) * (float)gy;
      o0.x = pk2(xx, yy);
    }
    *(uint4*)(ct + t * 16) = o0;
    *(uint4*)(ct + t * 16 + 8) = o1;
  }

  bf16x8 wfr[18];
  auto loadW = [&](int cc) {
    #pragma unroll
    for (int tap = 0; tap < 9; ++tap)
      #pragma unroll
      for (int hh = 0; hh < 2; ++hh)
        wfr[tap * 2 + hh] = *(const bf16x8*)(wcf +
            ((size_t)(((cc * 9 + tap) * 4 + kh * 2 + hh) * 2 + ntw)) * 512
            + lane * 8);
  };
  auto issue = [&](int buf, int cc) {
    #pragma unroll
    for (int k = 0; k < 8; ++k) {
      const char* src = (desc[k] == 0xFFFFFFFFu)
          ? (const char*)zb : (const char*)fb + desc[k] + cc * 128;
      gload_lds16(src, (char*)tile[buf] + (wv + 4 * k) * 1024);
    }
  };

  f32x16 acc[4] = {};

  issue(0, 0);
  loadW(0);
  __syncthreads();

  for (int cc = 0; cc < 4; ++cc) {
    if (cc < 3) issue((cc + 1) & 1, cc + 1);   // next chunk flies during MFMA
    const u16* tb = tile[cc & 1];
    #pragma unroll
    for (int tap = 0; tap < 9; ++tap) {
      const int dy = tap / 3, dx = tap - dy * 3;
      #pragma unroll
      for (int hh = 0; hh < 2; ++hh) {
        const bf16x8 bfr = wfr[tap * 2 + hh];
        #pragma unroll
        for (int ai = 0; ai < 4; ++ai) {
          const bf16x8 a = *(const bf16x8*)(tb +
              ((ai + dy) * 34 + l31 + dx) * 72 + (kh * 2 + hh) * 16 + l5 * 8);
          acc[ai] = __builtin_amdgcn_mfma_f32_32x32x16_bf16(a, bfr, acc[ai],
                                                            0, 0, 0);
        }
      }
    }
    if (cc < 3) loadW(cc + 1);                 // weights fly during barrier
    __syncthreads();
  }

  // coordinate K-step (kh==0 waves only)
  if (kh == 0) {
    #pragma unroll
    for (int tap = 0; tap < 9; ++tap) {
      const int dy = tap / 3, dx = tap - dy * 3;
      const bf16x8 bfr = *(const bf16x8*)(wcc +
          ((size_t)(tap * 2 + ntw)) * 512 + lane * 8);
      #pragma unroll
      for (int ai = 0; ai < 4; ++ai) {
        const bf16x8 a = *(const bf16x8*)(ct +
            ((ai + dy) * 34 + l31 + dx) * 16 + l5 * 8);
        acc[ai] = __builtin_amdgcn_mfma_f32_32x32x16_bf16(a, bfr, acc[ai],
                                                          0, 0, 0);
      }
    }
  }

  // kh reduction through dead buffer 0 (32 KB exactly)
  float* redk = (float*)&tile[0][0];
  if (kh == 1) {
    #pragma unroll
    for (int ai = 0; ai < 4; ++ai)
      #pragma unroll
      for (int r = 0; r < 16; ++r)
        redk[((ntw * 4 + ai) * 16 + r) * 64 + lane] = acc[ai][r];
  }
  __syncthreads();
  if (kh == 0) {
    const int oc = ntw * 32 + l31;
    const float inv = g[oc] * rsqrtf(v[oc] + EPSBN);
    const float sh = bb[oc] - m[oc] * inv + cb[oc] * inv;
    #pragma unroll
    for (int ai = 0; ai < 4; ++ai) {
      const int y = y0 + ai;
      #pragma unroll
      for (int r = 0; r < 16; ++r) {
        const float a = acc[ai][r] + redk[((ntw * 4 + ai) * 16 + r) * 64 + lane];
        const int xr = (r & 3) + 8 * (r >> 2) + 4 * l5;
        const float val = fmaxf(fmaf(a, inv, sh), 0.f);
        x1b[((size_t)((b * 96 + y) * 96 + x0 + xr)) * 64 + oc] = f2bf(val);
      }
    }
  }
}

// ---------------------------------------------------------------------------
// 64->64ch 3x3 conv (bf16 NHWC64 in). 256 thr, 4 waves.
// NN==2: waves (ntw, kh), 4 rows/wave. NN==1: waves (rp, kh), 2 rows/wave.
// Single-shot gload_lds staging + wfr[18] preload; kh LDS reduce.
// EPI: 0 = BN+ReLU -> bf16 ; 1 = +bias -> fp32 NHWC18 ; 2 = BN+ReLU +
//      1x1 out conv + sigmoid -> fp32 (B,96,96).
// ---------------------------------------------------------------------------
template<int NN, int EPI>
__global__ __launch_bounds__(256, 2) void conv64_kernel(
    const u16* __restrict__ xin, const u16* __restrict__ wf,
    const float* __restrict__ bias,
    const float* __restrict__ g, const float* __restrict__ bb,
    const float* __restrict__ m, const float* __restrict__ v,
    const float* __restrict__ ow, const float* __restrict__ ob,
    void* __restrict__ outp, const u32* __restrict__ zb)
{
  __shared__ __align__(16) u16 tile[16384];   // 32 KB, reused for reduce
  __shared__ float red2[2][128];
  const int t = threadIdx.x;
  const int wv = t >> 6, lane = t & 63;
  const int l31 = lane & 31, l5 = lane >> 5;
  const int ntw = (NN == 2) ? (wv & 1) : 0;
  const int rp  = (NN == 2) ? 0 : (wv & 1);
  const int kh  = wv >> 1;
  constexpr int NA = (NN == 2) ? 4 : 2;
  const int x0 = blockIdx.x * 32, y0 = blockIdx.y * 4, b = blockIdx.z;

  #pragma unroll
  for (int k = 0; k < 8; ++k) {
    const u32 d = stage_desc((wv + 4 * k) * 64 + lane, x0, y0, b, 128);
    const char* src = (d == 0xFFFFFFFFu) ? (const char*)zb
                                         : (const char*)xin + d;
    gload_lds16(src, (char*)tile + (wv + 4 * k) * 1024);
  }
  bf16x8 wfr[18];
  #pragma unroll
  for (int tap = 0; tap < 9; ++tap)
    #pragma unroll
    for (int hh = 0; hh < 2; ++hh) {
      const int h = kh * 2 + hh;
      const size_t f = (NN == 2) ? (size_t)((tap * 4 + h) * 2 + ntw)
                                 : (size_t)(tap * 4 + h);
      wfr[tap * 2 + hh] = *(const bf16x8*)(wf + f * 512 + lane * 8);
    }
  __syncthreads();

  f32x16 acc[NA] = {};
  #pragma unroll
  for (int tap = 0; tap < 9; ++tap) {
    const int dy = tap / 3, dx = tap - dy * 3;
    #pragma unroll
    for (int hh = 0; hh < 2; ++hh) {
      const bf16x8 bfr = wfr[tap * 2 + hh];
      #pragma unroll
      for (int ai = 0; ai < NA; ++ai) {
        const int rr = (NN == 2) ? ai : rp * 2 + ai;
        const bf16x8 a = *(const bf16x8*)(tile +
            ((rr + dy) * 34 + l31 + dx) * 72 + (kh * 2 + hh) * 16 + l5 * 8);
        acc[ai] = __builtin_amdgcn_mfma_f32_32x32x16_bf16(a, bfr, acc[ai],
                                                          0, 0, 0);
      }
    }
  }

  // kh reduction through the dead tile
  float* redk = (float*)tile;
  __syncthreads();                       // all tile reads done
  if (kh == 1) {
    #pragma unroll
    for (int ai = 0; ai < NA; ++ai) {
      const int slot = (NN == 2) ? (ntw * 4 + ai) : (rp * 2 + ai);
      #pragma unroll
      for (int r = 0; r < 16; ++r)
        redk[(slot * 16 + r) * 64 + lane] = acc[ai][r];
    }
  }
  __syncthreads();

  if constexpr (EPI == 0) {
    if (kh == 0) {
      u16* xo = (u16*)outp;
      const int oc = ntw * 32 + l31;
      const float inv = g[oc] * rsqrtf(v[oc] + EPSBN);
      const float sh = bb[oc] - m[oc] * inv;
      #pragma unroll
      for (int ai = 0; ai < NA; ++ai) {
        const int y = y0 + ai;
        #pragma unroll
        for (int r = 0; r < 16; ++r) {
          const float a = acc[ai][r] + redk[((ntw * 4 + ai) * 16 + r) * 64 + lane];
          const int xr = (r & 3) + 8 * (r >> 2) + 4 * l5;
          const float val = fmaxf(fmaf(a, inv, sh), 0.f);
          xo[((size_t)((b * 96 + y) * 96 + x0 + xr)) * 64 + oc] = f2bf(val);
        }
      }
    }
  } else if constexpr (EPI == 1) {
    if (kh == 0) {
      float* fo = (float*)outp;
      #pragma unroll
      for (int ai = 0; ai < NA; ++ai) {
        const int y = y0 + rp * 2 + ai;
        float av[16];
        #pragma unroll
        for (int r = 0; r < 16; ++r)
          av[r] = acc[ai][r] + redk[((rp * 2 + ai) * 16 + r) * 64 + lane];
        if (l31 < 18) {
          const float bs = bias[l31];
          #pragma unroll
          for (int r = 0; r < 16; ++r) {
            const int xr = (r & 3) + 8 * (r >> 2) + 4 * l5;
            fo[((size_t)((b * 96 + y) * 96 + x0 + xr)) * 18 + l31] = av[r] + bs;
          }
        }
      }
    }
  } else {  // EPI == 2
    if (kh == 0) {
      const int oc = ntw * 32 + l31;
      const float inv = g[oc] * rsqrtf(v[oc] + EPSBN);
      const float sh = bb[oc] - m[oc] * inv;
      const float wo = ow[oc];
      #pragma unroll
      for (int ai = 0; ai < NA; ++ai) {
        float pr[16];
        #pragma unroll
        for (int r = 0; r < 16; ++r) {
          const float a = acc[ai][r] + redk[((ntw * 4 + ai) * 16 + r) * 64 + lane];
          const float val = fmaxf(fmaf(a, inv, sh), 0.f);
          pr[r] = val * wo;
        }
        #pragma unroll
        for (int mask = 1; mask <= 16; mask <<= 1)
          #pragma unroll
          for (int r = 0; r < 16; ++r)
            pr[r] += __shfl_xor(pr[r], mask);
        if (l31 == 0) {
          #pragma unroll
          for (int r = 0; r < 16; ++r) {
            const int xr = (r & 3) + 8 * (r >> 2) + 4 * l5;
            red2[ntw][ai * 32 + xr] = pr[r];
          }
        }
      }
    }
    __syncthreads();
    if (t < 128) {
      float* fo = (float*)outp;
      const int yy = y0 + (t >> 5), xx = x0 + (t & 31);
      const float val = red2[0][t] + red2[1][t] + ob[0];
      fo[(size_t)(b * 96 + yy) * 96 + xx] = 1.f / (1.f + expf(-val));
    }
  }
}

// ---------------------------------------------------------------------------
// Deformable conv 64->64 + BN2 + ReLU -> x2b (round-4 version, unchanged).
// ---------------------------------------------------------------------------
__global__ __launch_bounds__(512, 4) void deform_kernel(
    const u16* __restrict__ x1b, const float* __restrict__ off,
    const u16* __restrict__ wdf,
    const float* __restrict__ g, const float* __restrict__ bb,
    const float* __restrict__ m, const float* __restrict__ v,
    u16* __restrict__ x2b)
{
  __shared__ __align__(16) u16 s[2 * 128 * 72];   // 36864 B
  __shared__ float offs[128 * 18];                //  9216 B
  const int t = threadIdx.x;
  const int wv = t >> 6, lane = t & 63;
  const int l31 = lane & 31, l5 = lane >> 5;
  const int mt = wv & 3, ntw = wv >> 2;
  const int x0 = blockIdx.x * 16, y0 = blockIdx.y * 8, b = blockIdx.z;

  {
    float po[5];
    #pragma unroll
    for (int r = 0; r < 5; ++r) {
      const int i = t + r * 512;
      po[r] = 0.f;
      if (i < 2304) {
        const int p = i / 18, c = i - p * 18;
        const int gy = y0 + (p >> 4), gx = x0 + (p & 15);
        po[r] = off[((size_t)((b * 96 + gy) * 96 + gx)) * 18 + c];
      }
    }
    #pragma unroll
    for (int r = 0; r < 5; ++r) {
      const int i = t + r * 512;
      if (i < 2304) offs[i] = po[r];
    }
  }
  __syncthreads();

  const int sp = t >> 2, part = t & 3;
  const int sy = y0 + (sp >> 4), sx = x0 + (sp & 15);

  uint4 gbuf[8];
  float w4[4];

  auto prefetch = [&](int k) {
    const float oy = offs[sp * 18 + 2 * k];
    const float ox = offs[sp * 18 + 2 * k + 1];
    const float py = (float)(sy + k / 3 - 1) + oy;
    const float px = (float)(sx + k % 3 - 1) + ox;
    const float yf = floorf(py), xf = floorf(px);
    const float fy = py - yf, fx = px - xf;
    const int yi = (int)yf, xi = (int)xf;
    #pragma unroll
    for (int cor = 0; cor < 4; ++cor) {
      const int cy = yi + (cor >> 1), cx = xi + (cor & 1);
      const uint4 z = {0u, 0u, 0u, 0u};
      gbuf[2 * cor] = z; gbuf[2 * cor + 1] = z;
      const float wy = (cor & 2) ? fy : 1.f - fy;
      const float wx = (cor & 1) ? fx : 1.f - fx;
      w4[cor] = 0.f;
      if ((unsigned)cy < 96u && (unsigned)cx < 96u) {
        w4[cor] = wy * wx;
        const u16* p = x1b + ((size_t)((b * 96 + cy) * 96 + cx)) * 64
                       + part * 16;
        gbuf[2 * cor]     = *(const uint4*)p;
        gbuf[2 * cor + 1] = *(const uint4*)(p + 8);
      }
    }
  };
  auto combine = [&](u16* dst) {
    float val[16];
    #pragma unroll
    for (int j = 0; j < 16; ++j) val[j] = 0.f;
    #pragma unroll
    for (int cor = 0; cor < 4; ++cor) {
      const float wgt = w4[cor];
      const u32 uu[8] = {gbuf[2 * cor].x, gbuf[2 * cor].y,
                         gbuf[2 * cor].z, gbuf[2 * cor].w,
                         gbuf[2 * cor + 1].x, gbuf[2 * cor + 1].y,
                         gbuf[2 * cor + 1].z, gbuf[2 * cor + 1].w};
      #pragma unroll
      for (int u = 0; u < 8; ++u) {
        val[2 * u]     = fmaf(wgt, lo2f(uu[u]), val[2 * u]);
        val[2 * u + 1] = fmaf(wgt, hi2f(uu[u]), val[2 * u + 1]);
      }
    }
    u32 pk[8];
    #pragma unroll
    for (int u = 0; u < 8; ++u) pk[u] = pk2(val[2 * u], val[2 * u + 1]);
    uint4 w0 = {pk[0], pk[1], pk[2], pk[3]};
    uint4 w1 = {pk[4], pk[5], pk[6], pk[7]};
    *(uint4*)(dst + sp * 72 + part * 16) = w0;
    *(uint4*)(dst + sp * 72 + part * 16 + 8) = w1;
  };

  f32x16 acc = {};

  prefetch(0);
  combine(s);          // buffer 0
  __syncthreads();

  for (int k = 0; k < 9; ++k) {
    u16* cur = s + (k & 1) * 9216;
    if (k < 8) prefetch(k + 1);          // gathers fly during MFMAs
    #pragma unroll
    for (int h = 0; h < 4; ++h) {
      const bf16x8 afr = *(const bf16x8*)(cur + (mt * 32 + l31) * 72
                                          + h * 16 + l5 * 8);
      const bf16x8 bfr = *(const bf16x8*)(wdf +
          ((size_t)((k * 4 + h) * 2 + ntw)) * 512 + lane * 8);
      acc = __builtin_amdgcn_mfma_f32_32x32x16_bf16(afr, bfr, acc, 0, 0, 0);
    }
    if (k < 8) combine(s + ((k + 1) & 1) * 9216);
    __syncthreads();
  }

  const int oc = ntw * 32 + l31;
  const float inv = g[oc] * rsqrtf(v[oc] + EPSBN);
  const float sh = bb[oc] - m[oc] * inv;
  #pragma unroll
  for (int r = 0; r < 16; ++r) {
    const int pxi = mt * 32 + (r & 3) + 8 * (r >> 2) + 4 * l5;
    const int y = y0 + (pxi >> 4), x = x0 + (pxi & 15);
    const float val = fmaxf(fmaf(acc[r], inv, sh), 0.f);
    x2b[((size_t)((b * 96 + y) * 96 + x)) * 64 + oc] = f2bf(val);
  }
}

extern "C" void kernel_launch(void* const* d_in, const int* in_sizes, int n_in,
                              void* d_out, int out_size, void* d_ws,
                              size_t ws_size, hipStream_t stream)
{
  (void)in_sizes; (void)n_in; (void)out_size; (void)ws_size;
  const float* features = (const float*)d_in[0];
  const float* coord_w  = (const float*)d_in[1];
  const float* coord_b  = (const float*)d_in[2];
  const float* bn1g = (const float*)d_in[3];
  const float* bn1b = (const float*)d_in[4];
  const float* bn1m = (const float*)d_in[5];
  const float* bn1v = (const float*)d_in[6];
  const float* off_w = (const float*)d_in[7];
  const float* off_b = (const float*)d_in[8];
  const float* dc_w  = (const float*)d_in[9];
  const float* bn2g = (const float*)d_in[10];
  const float* bn2b = (const float*)d_in[11];
  const float* bn2m = (const float*)d_in[12];
  const float* bn2v = (const float*)d_in[13];
  const float* r1_w = (const float*)d_in[14];
  const float* bn3g = (const float*)d_in[15];
  const float* bn3b = (const float*)d_in[16];
  const float* bn3m = (const float*)d_in[17];
  const float* bn3v = (const float*)d_in[18];
  const float* r2_w = (const float*)d_in[19];
  const float* bn4g = (const float*)d_in[20];
  const float* bn4b = (const float*)d_in[21];
  const float* bn4m = (const float*)d_in[22];
  const float* bn4v = (const float*)d_in[23];
  const float* out_w = (const float*)d_in[24];
  const float* out_b = (const float*)d_in[25];

  char* W = (char*)d_ws;
  float* offb = (float*)W;                         //  5,308,416 B
  u16*   x1b  = (u16*)(W + 5308416);               //  9,437,184 B
  u16*   x2b  = (u16*)(W + 14745600);
  u16*   x3b  = (u16*)(W + 24182784);
  u16*   wcf  = (u16*)(W + 33619968);
  u16*   wcc  = wcf + N_WCF;
  u16*   wof  = wcc + N_WCC;
  u16*   wdf  = wof + N_WOF;
  u16*   wr1  = wdf + N_W64;
  u16*   wr2  = wr1 + N_W64;
  u16*   fb   = (u16*)(W + 34191360);              // 37,748,736 B bf16 feats
  u32*   zb   = (u32*)(W + 71940096);              // 256 B zero line

  prep_kernel<<<FBK_BLOCKS + WT_BLOCKS, 256, 0, stream>>>(
      features, coord_w, off_w, dc_w, r1_w, r2_w,
      fb, wcf, wcc, wof, wdf, wr1, wr2, zb);

  dim3 grid(3, 24, 8);   // 32x4 tiles
  dim3 gridD(6, 12, 8);  // 16x8 tiles (deform)

  coord_conv_kernel<<<grid, 256, 0, stream>>>(
      fb, wcf, wcc, coord_b, bn1g, bn1b, bn1m, bn1v, x1b, zb);
  conv64_kernel<1, 1><<<grid, 256, 0, stream>>>(
      x1b, wof, off_b, nullptr, nullptr, nullptr, nullptr, nullptr, nullptr,
      (void*)offb, zb);
  deform_kernel<<<gridD, 512, 0, stream>>>(
      x1b, offb, wdf, bn2g, bn2b, bn2m, bn2v, x2b);
  conv64_kernel<2, 0><<<grid, 256, 0, stream>>>(
      x2b, wr1, nullptr, bn3g, bn3b, bn3m, bn3v, nullptr, nullptr,
      (void*)x3b, zb);
  conv64_kernel<2, 2><<<grid, 256, 0, stream>>>(
      x3b, wr2, nullptr, bn4g, bn4b, bn4m, bn4v, out_w, out_b, d_out, zb);
}